// Round 5
// baseline (67644.214 us; speedup 1.0000x reference)
//
#include <hip/hip_runtime.h>
#include <hip/hip_cooperative_groups.h>
#include <math.h>

namespace cg = cooperative_groups;

#define N_ITERS 200
#define B_DIM 128
#define K_DIM 10000
#define KP2 10240           /* Z cols / Dth cols */
#define KDH 10112           /* Dh rows / R cols: 79*128 */
#define RS  10112
#define D_DIM 1024
#define ALPHA_F 4.8828125e-6f   /* 0.01 / 2048 */
#define NBLK 256
#define NTHR 512

typedef unsigned short u16;
typedef __attribute__((ext_vector_type(8))) short bf16x8;
typedef __attribute__((ext_vector_type(4))) float f32x4;
#define MFMA __builtin_amdgcn_mfma_f32_16x16x32_bf16

__device__ __forceinline__ u16 f2bf(float x) {
    unsigned u = __float_as_uint(x);
    u += 0x7fff + ((u >> 16) & 1);
    return (u16)(u >> 16);
}
__device__ __forceinline__ float bf2f(u16 h) {
    return __uint_as_float(((unsigned)h) << 16);
}
__device__ __forceinline__ void split2(float x, u16& h, u16& l) {
    u16 hh = f2bf(x);
    h = hh;
    l = f2bf(x - bf2f(hh));
}
__device__ __forceinline__ int swz(int r) { return (r & 3) ^ ((r >> 2) & 1); }

__device__ __forceinline__ void gl2lds16(const u16* g, u16* l) {
    __builtin_amdgcn_global_load_lds(
        (const __attribute__((address_space(1))) unsigned int*)g,
        (__attribute__((address_space(3))) unsigned int*)l,
        16, 0, 0);
}

// ---------------------------------------------------------------------------
// gcore: 64x128 output tile, both operands K-major split-bf16, dbuf LDS.
// A-tile 64 rows (staged by t<256), B-tile 128 rows (all threads).
// LDS layout per stage (u16 units): Ah@0(2048) Al@2048 Bh@4096(4096) Bl@8192;
// stage stride 12288 (48 KB total).
// Wave w: wm=(w>>2)*32, wn=(w&3)*32; frags 2x2; 12 MFMA : 8 b128 per step.
// ---------------------------------------------------------------------------
__device__ __forceinline__ void gcore(const u16* __restrict__ Ahg, const u16* __restrict__ Alg, size_t sA,
                                      const u16* __restrict__ Bhg, const u16* __restrict__ Blg, size_t sB,
                                      int ksteps, u16* lds, int t, f32x4 acc[2][2]) {
    int w = t >> 6, lane = t & 63, quad = lane >> 4, lr = lane & 15;
    int wm = (w >> 2) * 32, wn = (w & 3) * 32;
    int r0 = t >> 2, qs = t & 3;
    int r0A = r0 & 63;
    int qA = qs ^ swz(r0A);
    int qB = qs ^ swz(r0);
    const u16* gAh = Ahg + (size_t)r0A * sA + qA * 8;
    const u16* gAl = Alg + (size_t)r0A * sA + qA * 8;
    const u16* gBh = Bhg + (size_t)r0 * sB + qB * 8;
    const u16* gBl = Blg + (size_t)r0 * sB + qB * 8;
    int dA = t * 8;            // A dest (t<256): 4 KB per array
    int offA[2], offB[2];
    #pragma unroll
    for (int mi = 0; mi < 2; ++mi) { int rr = wm + mi * 16 + lr; offA[mi] = rr * 32 + ((quad ^ swz(rr)) * 8); }
    #pragma unroll
    for (int ni = 0; ni < 2; ++ni) { int rr = wn + ni * 16 + lr; offB[ni] = rr * 32 + ((quad ^ swz(rr)) * 8); }
    #pragma unroll
    for (int mi = 0; mi < 2; ++mi)
        #pragma unroll
        for (int ni = 0; ni < 2; ++ni) acc[mi][ni] = (f32x4){0.f, 0.f, 0.f, 0.f};
    {
        if (t < 256) { gl2lds16(gAh, lds + dA); gl2lds16(gAl, lds + 2048 + dA); }
        gl2lds16(gBh, lds + 4096 + dA);
        gl2lds16(gBl, lds + 8192 + dA);
    }
    for (int s = 0; s < ksteps; ++s) {
        __syncthreads();
        if (s + 1 < ksteps) {
            u16* b = lds + ((s + 1) & 1) * 12288;
            int c = (s + 1) * 32;
            if (t < 256) { gl2lds16(gAh + c, b + dA); gl2lds16(gAl + c, b + 2048 + dA); }
            gl2lds16(gBh + c, b + 4096 + dA);
            gl2lds16(gBl + c, b + 8192 + dA);
        }
        u16* b = lds + (s & 1) * 12288;
        bf16x8 aH[2], aL[2], bH[2], bL[2];
        #pragma unroll
        for (int mi = 0; mi < 2; ++mi) { aH[mi] = *(const bf16x8*)&b[offA[mi]]; aL[mi] = *(const bf16x8*)&b[2048 + offA[mi]]; }
        #pragma unroll
        for (int ni = 0; ni < 2; ++ni) { bH[ni] = *(const bf16x8*)&b[4096 + offB[ni]]; bL[ni] = *(const bf16x8*)&b[8192 + offB[ni]]; }
        #pragma unroll
        for (int mi = 0; mi < 2; ++mi)
            #pragma unroll
            for (int ni = 0; ni < 2; ++ni) {
                acc[mi][ni] = MFMA(aL[mi], bH[ni], acc[mi][ni], 0, 0, 0);
                acc[mi][ni] = MFMA(aH[mi], bL[ni], acc[mi][ni], 0, 0, 0);
                acc[mi][ni] = MFMA(aH[mi], bH[ni], acc[mi][ni], 0, 0, 0);
            }
    }
    __syncthreads();
}

// ---------------------------------------------------------------------------
// g1_tile: U-partial = Z[128, ks*1280 : +1280] @ Dth-slice. Tile 128x64.
// bx<128: n-tile = bx&15 (64 wide over d), ks = bx>>4 (8 splits), 40 K-steps.
// LDS per stage: Ah@0(4096) Al@4096 Bh@8192(2048) Bl@10240; stride 12288.
// Wave w: wm=(w>>1)*32, wn=(w&1)*32; frags 2x2.
// ---------------------------------------------------------------------------
__device__ __forceinline__ void g1_tile(const u16* __restrict__ Azh, const u16* __restrict__ Azl,
                                        const u16* __restrict__ Bth, const u16* __restrict__ Btl,
                                        float* __restrict__ Up, u16* lds, int bx, int t) {
    int n0 = (bx & 15) * 64;
    int ks = bx >> 4;
    size_t kbase = (size_t)ks * 1280;
    int w = t >> 6, lane = t & 63, quad = lane >> 4, lr = lane & 15;
    int wm = (w >> 1) * 32, wn = (w & 1) * 32;
    int r0 = t >> 2, qs = t & 3;
    int r0B = r0 & 63;
    int qA = qs ^ swz(r0);
    int qB = qs ^ swz(r0B);
    const u16* gAh = Azh + (size_t)r0 * KP2 + kbase + qA * 8;
    const u16* gAl = Azl + (size_t)r0 * KP2 + kbase + qA * 8;
    const u16* gBh = Bth + (size_t)(n0 + r0B) * KP2 + kbase + qB * 8;
    const u16* gBl = Btl + (size_t)(n0 + r0B) * KP2 + kbase + qB * 8;
    int dA = t * 8;
    int offA[2], offB[2];
    #pragma unroll
    for (int mi = 0; mi < 2; ++mi) { int rr = wm + mi * 16 + lr; offA[mi] = rr * 32 + ((quad ^ swz(rr)) * 8); }
    #pragma unroll
    for (int ni = 0; ni < 2; ++ni) { int rr = wn + ni * 16 + lr; offB[ni] = rr * 32 + ((quad ^ swz(rr)) * 8); }
    f32x4 acc[2][2];
    #pragma unroll
    for (int mi = 0; mi < 2; ++mi)
        #pragma unroll
        for (int ni = 0; ni < 2; ++ni) acc[mi][ni] = (f32x4){0.f, 0.f, 0.f, 0.f};
    {
        gl2lds16(gAh, lds + dA);
        gl2lds16(gAl, lds + 4096 + dA);
        if (t < 256) { gl2lds16(gBh, lds + 8192 + dA); gl2lds16(gBl, lds + 10240 + dA); }
    }
    for (int s = 0; s < 40; ++s) {
        __syncthreads();
        if (s + 1 < 40) {
            u16* b = lds + ((s + 1) & 1) * 12288;
            int c = (s + 1) * 32;
            gl2lds16(gAh + c, b + dA);
            gl2lds16(gAl + c, b + 4096 + dA);
            if (t < 256) { gl2lds16(gBh + c, b + 8192 + dA); gl2lds16(gBl + c, b + 10240 + dA); }
        }
        u16* b = lds + (s & 1) * 12288;
        bf16x8 aH[2], aL[2], bH[2], bL[2];
        #pragma unroll
        for (int mi = 0; mi < 2; ++mi) { aH[mi] = *(const bf16x8*)&b[offA[mi]]; aL[mi] = *(const bf16x8*)&b[4096 + offA[mi]]; }
        #pragma unroll
        for (int ni = 0; ni < 2; ++ni) { bH[ni] = *(const bf16x8*)&b[8192 + offB[ni]]; bL[ni] = *(const bf16x8*)&b[10240 + offB[ni]]; }
        #pragma unroll
        for (int mi = 0; mi < 2; ++mi)
            #pragma unroll
            for (int ni = 0; ni < 2; ++ni) {
                acc[mi][ni] = MFMA(aL[mi], bH[ni], acc[mi][ni], 0, 0, 0);
                acc[mi][ni] = MFMA(aH[mi], bL[ni], acc[mi][ni], 0, 0, 0);
                acc[mi][ni] = MFMA(aH[mi], bH[ni], acc[mi][ni], 0, 0, 0);
            }
    }
    __syncthreads();
    float* o = Up + (size_t)ks * (B_DIM * D_DIM);
    #pragma unroll
    for (int mi = 0; mi < 2; ++mi)
        #pragma unroll
        for (int ni = 0; ni < 2; ++ni) {
            int d = n0 + wn + ni * 16 + lr;
            #pragma unroll
            for (int r = 0; r < 4; ++r) {
                int i2 = wm + mi * 16 + quad * 4 + r;
                o[(size_t)i2 * D_DIM + d] = acc[mi][ni][r];
            }
        }
}

// ---------------------------------------------------------------------------
__global__ __launch_bounds__(NTHR, 1) void k_mega(
    const float* __restrict__ emb, const float* __restrict__ Dm,
    float* __restrict__ out,
    u16* __restrict__ Zh, u16* __restrict__ Zl,
    u16* __restrict__ Uh, u16* __restrict__ Ul,
    float* __restrict__ RG, float* __restrict__ Up,
    float* __restrict__ uvec, float* __restrict__ wv, float* __restrict__ scal,
    u16* __restrict__ Dh, u16* __restrict__ Dl,
    u16* __restrict__ Dth, u16* __restrict__ Dtl)
{
    cg::grid_group grid = cg::this_grid();
    __shared__ __align__(16) u16 lds[24576];   // 48 KB
    const int bx = blockIdx.x;
    const int t = threadIdx.x;

    // ---- phase 0a: zero everything we accumulate into ----
    {
        int idx = bx * NTHR + t, stride = NBLK * NTHR;
        for (int i = idx; i < B_DIM * K_DIM + 1; i += stride) out[i] = 0.f;
        unsigned* zh = (unsigned*)Zh; unsigned* zl = (unsigned*)Zl;
        for (int i = idx; i < B_DIM * KP2 / 2; i += stride) { zh[i] = 0u; zl[i] = 0u; }
        for (int i = idx; i < D_DIM; i += stride) uvec[i] = 0.f;
        for (int i = idx; i < 64; i += stride) scal[i] = 0.f;
    }
    __threadfence(); grid.sync();

    // ---- phase 0b: convert D (split + transpose), split emb, colsum u0 ----
    {
        u16* Th = lds;               // [32][33]
        u16* Tl = lds + 1056;
        int tx = t & 31, ty = t >> 5;   // ty 0..15
        for (int tile = bx; tile < 10240; tile += NBLK) {   // 320 k-tiles x 32 d-tiles
            int tk = tile >> 5, td = tile & 31;
            int k0 = tk * 32, d0 = td * 32;
            #pragma unroll
            for (int r = 0; r < 2; ++r) {
                int row = ty + r * 16;
                int krow = k0 + row;
                float val = (krow < K_DIM) ? Dm[(size_t)krow * D_DIM + d0 + tx] : 0.f;
                u16 h, l; split2(val, h, l);
                if (krow < KDH) {
                    Dh[(size_t)krow * D_DIM + d0 + tx] = h;
                    Dl[(size_t)krow * D_DIM + d0 + tx] = l;
                }
                Th[row * 33 + tx] = h;
                Tl[row * 33 + tx] = l;
            }
            __syncthreads();
            #pragma unroll
            for (int r = 0; r < 2; ++r) {
                int dr = ty + r * 16;
                Dth[(size_t)(d0 + dr) * KP2 + k0 + tx] = Th[tx * 33 + dr];
                Dtl[(size_t)(d0 + dr) * KP2 + k0 + tx] = Tl[tx * 33 + dr];
            }
            __syncthreads();
        }
        {   // emb split -> Uh/Ul (used as A for the R-precompute GEMM)
            int i = bx * NTHR + t;      // exactly 131072 threads
            u16 h, l; split2(emb[i], h, l);
            Uh[i] = h; Ul[i] = l;
        }
        if (bx < 250) {                 // u0 = ones(K)@D = colsum(D)
            float a0 = 0.f, a1 = 0.f;
            for (int k = bx * 40; k < bx * 40 + 40; ++k) {
                const float* row = Dm + (size_t)k * D_DIM;
                a0 += row[t];
                a1 += row[t + 512];
            }
            atomicAdd(&uvec[t], a0);
            atomicAdd(&uvec[t + 512], a1);
        }
    }
    __threadfence(); grid.sync();

    // ---- phase 1: Gram G = D^T D  (128 blocks, 64x128 tiles, K=10240) ----
    if (bx < 128) {
        int m0 = (bx & 15) * 64, n0 = (bx >> 4) * 128;
        f32x4 acc[2][2];
        gcore(Dth + (size_t)m0 * KP2, Dtl + (size_t)m0 * KP2, KP2,
              Dth + (size_t)n0 * KP2, Dtl + (size_t)n0 * KP2, KP2,
              320, lds, t, acc);
        int w = t >> 6, lane = t & 63, quad = lane >> 4, lr = lane & 15;
        int wm = (w >> 2) * 32, wn = (w & 3) * 32;
        #pragma unroll
        for (int mi = 0; mi < 2; ++mi)
            #pragma unroll
            for (int ni = 0; ni < 2; ++ni) {
                int c = n0 + wn + ni * 16 + lr;
                #pragma unroll
                for (int r = 0; r < 4; ++r) {
                    int i2 = m0 + wm + mi * 16 + quad * 4 + r;
                    RG[(size_t)i2 * 1024 + c] = acc[mi][ni][r];
                }
            }
    }
    __threadfence(); grid.sync();

    // ---- phase 2: power iteration in u-space (31 rounds) ----
    for (int pw = 0; pw <= 30; ++pw) {
        {   // P1: wv[c] = dot(u, G[c,:]), and X += wv[c]*u[c]
            int c = bx * 4 + (t >> 7);
            int rb = t & 127;
            float a = 0.f;
            #pragma unroll
            for (int j = 0; j < 8; ++j) { int r = rb + j * 128; a = fmaf(uvec[r], RG[(size_t)c * 1024 + r], a); }
            #pragma unroll
            for (int o2 = 32; o2 > 0; o2 >>= 1) a += __shfl_down(a, o2, 64);
            float* red = (float*)lds;
            __syncthreads();
            if ((t & 63) == 0) red[t >> 6] = a;
            __syncthreads();
            if (t < 4) {
                float wvc = red[t * 2] + red[t * 2 + 1];
                wv[bx * 4 + t] = wvc;
                atomicAdd(&scal[2 + pw], wvc * uvec[bx * 4 + t]);
            }
        }
        __threadfence(); grid.sync();
        {   // P2: u = wv/sqrt(X), or finalize step/thresh
            float X = scal[2 + pw];
            if (pw < 30) {
                if ((t & 127) == 0) {
                    int c = bx * 4 + (t >> 7);
                    uvec[c] = wv[c] * rsqrtf(X);
                }
            } else if (bx == 0 && t == 0) {
                float stepv = 1024.0f / sqrtf(X);   // L = sqrt(X)/n
                scal[0] = stepv;
                scal[1] = stepv * ALPHA_F;
            }
        }
        __threadfence(); grid.sync();
    }

    // ---- phase 3: R = emb @ D^T / n  (158 blocks, 64x128 tiles) ----
    if (bx < 158) {
        int m0 = (bx & 1) * 64, n0 = (bx >> 1) * 128;
        f32x4 acc[2][2];
        gcore(Uh + (size_t)m0 * D_DIM, Ul + (size_t)m0 * D_DIM, D_DIM,
              Dh + (size_t)n0 * D_DIM, Dl + (size_t)n0 * D_DIM, D_DIM,
              32, lds, t, acc);
        int w = t >> 6, lane = t & 63, quad = lane >> 4, lr = lane & 15;
        int wm = (w >> 2) * 32, wn = (w & 3) * 32;
        const float invN = 1.f / 1024.f;
        #pragma unroll
        for (int mi = 0; mi < 2; ++mi)
            #pragma unroll
            for (int ni = 0; ni < 2; ++ni) {
                int kc = n0 + wn + ni * 16 + lr;
                #pragma unroll
                for (int r = 0; r < 4; ++r) {
                    int i2 = m0 + wm + mi * 16 + quad * 4 + r;
                    RG[(size_t)i2 * RS + kc] = acc[mi][ni][r] * invN;
                }
            }
    }
    __threadfence(); grid.sync();

    float stepv = scal[0], thv = scal[1];
    const float invN = 1.f / 1024.f;

    // ---- FISTA main loop ----
    double tm_ = 1.0;
    for (int it = 0; it < N_ITERS; ++it) {
        double tn_ = 0.5 * (1.0 + sqrt(1.0 + 4.0 * tm_ * tm_));
        float mom = (float)((tm_ - 1.0) / tn_);
        tm_ = tn_;

        if (bx < 128) g1_tile(Zh, Zl, Dth, Dtl, Up, lds, bx, t);
        __threadfence(); grid.sync();

        {   // reduce 8 partials -> split bf16 U
            int e = bx * NTHR + t;
            float a = 0.f;
            #pragma unroll
            for (int s2 = 0; s2 < 8; ++s2) a += Up[(size_t)s2 * (B_DIM * D_DIM) + e];
            u16 h, l; split2(a, h, l);
            Uh[e] = h; Ul[e] = l;
        }
        __threadfence(); grid.sync();

        if (bx < 158) {   // grad + prox + momentum, fused
            int m0 = (bx & 1) * 64, n0 = (bx >> 1) * 128;
            f32x4 acc[2][2];
            gcore(Uh + (size_t)m0 * D_DIM, Ul + (size_t)m0 * D_DIM, D_DIM,
                  Dh + (size_t)n0 * D_DIM, Dl + (size_t)n0 * D_DIM, D_DIM,
                  32, lds, t, acc);
            int w = t >> 6, lane = t & 63, quad = lane >> 4, lr = lane & 15;
            int wm = (w >> 2) * 32, wn = (w & 3) * 32;
            int writeW = (it == N_ITERS - 1);
            #pragma unroll
            for (int mi = 0; mi < 2; ++mi)
                #pragma unroll
                for (int ni = 0; ni < 2; ++ni) {
                    int kc = n0 + wn + ni * 16 + lr;
                    #pragma unroll
                    for (int r = 0; r < 4; ++r) {
                        int i2 = m0 + wm + mi * 16 + quad * 4 + r;
                        size_t iz = (size_t)i2 * KP2 + kc;
                        float g = acc[mi][ni][r] * invN - RG[(size_t)i2 * RS + kc];
                        float z = bf2f(Zh[iz]) + bf2f(Zl[iz]);
                        float wold = (kc < K_DIM) ? out[(size_t)i2 * K_DIM + kc] : 0.f;
                        float wnew = fmaxf(z - stepv * g - thv, 0.f);
                        float zn = wnew + mom * (wnew - wold);
                        if (kc < K_DIM) out[(size_t)i2 * K_DIM + kc] = wnew;
                        u16 h, l;
                        split2(writeW ? wnew : zn, h, l);
                        Zh[iz] = h; Zl[iz] = l;
                    }
                }
        }
        __threadfence(); grid.sync();
    }

    // ---- recon = W@D (Zh/Zl hold split W after last iter) ----
    if (bx < 128) g1_tile(Zh, Zl, Dth, Dtl, Up, lds, bx, t);
    __threadfence(); grid.sync();
    {
        int e = bx * NTHR + t;
        float a = 0.f;
        #pragma unroll
        for (int s2 = 0; s2 < 8; ++s2) a += Up[(size_t)s2 * (B_DIM * D_DIM) + e];
        u16 h, l; split2(a, h, l);
        Uh[e] = h; Ul[e] = l;
    }
    __threadfence(); grid.sync();

    // ---- score (block 0) ----
    if (bx == 0) {
        int w = t >> 6, lane = t & 63;
        float part = 0.f;
        for (int row = w; row < B_DIM; row += 8) {
            float rr = 0.f, re = 0.f;
            for (int j = lane; j < D_DIM; j += 64) {
                int i2 = row * D_DIM + j;
                float x = bf2f(Uh[i2]) + bf2f(Ul[i2]);
                rr = fmaf(x, x, rr);
                re = fmaf(x, emb[i2], re);
            }
            #pragma unroll
            for (int o2 = 32; o2 > 0; o2 >>= 1) {
                rr += __shfl_down(rr, o2, 64);
                re += __shfl_down(re, o2, 64);
            }
            if (lane == 0) part += re / (sqrtf(rr) + 1e-12f);
        }
        float* sred = (float*)lds;
        __syncthreads();
        if (lane == 0) sred[w] = part;
        __syncthreads();
        if (t == 0) {
            float s = 0.f;
            #pragma unroll
            for (int w2 = 0; w2 < 8; ++w2) s += sred[w2];
            out[B_DIM * K_DIM] = s;
        }
    }
}

// ---------------------------------------------------------------------------
extern "C" void kernel_launch(void* const* d_in, const int* in_sizes, int n_in,
                              void* d_out, int out_size, void* d_ws, size_t ws_size,
                              hipStream_t stream) {
    const float* emb = (const float*)d_in[0];   // [128,1024]
    const float* Dm  = (const float*)d_in[1];   // [10000,1024]
    float* out = (float*)d_out;

    size_t off = 0;
    auto carve = [&](size_t bytes) -> void* {
        void* r = (char*)d_ws + off;
        off += (bytes + 255) & ~(size_t)255;
        return r;
    };
    float* RG   = (float*)carve((size_t)B_DIM * RS * 4);          // 5.18 MB (G aliased, then R)
    u16*   Zh   = (u16*)carve((size_t)B_DIM * KP2 * 2);           // 2.62 MB
    u16*   Zl   = (u16*)carve((size_t)B_DIM * KP2 * 2);
    u16*   Uh   = (u16*)carve((size_t)B_DIM * D_DIM * 2);         // 0.26 MB
    u16*   Ul   = (u16*)carve((size_t)B_DIM * D_DIM * 2);
    float* Up   = (float*)carve((size_t)8 * B_DIM * D_DIM * 4);   // 4.19 MB
    float* uvec = (float*)carve(D_DIM * 4);
    float* wv   = (float*)carve(D_DIM * 4);
    float* scal = (float*)carve(64 * 4);
    u16*   Dh   = (u16*)carve((size_t)KDH * D_DIM * 2);           // 20.71 MB
    u16*   Dl   = (u16*)carve((size_t)KDH * D_DIM * 2);
    u16*   Dth  = (u16*)carve((size_t)D_DIM * KP2 * 2);           // 20.97 MB
    u16*   Dtl  = (u16*)carve((size_t)D_DIM * KP2 * 2);

    void* args[] = {
        (void*)&emb, (void*)&Dm, (void*)&out,
        (void*)&Zh, (void*)&Zl, (void*)&Uh, (void*)&Ul,
        (void*)&RG, (void*)&Up, (void*)&uvec, (void*)&wv, (void*)&scal,
        (void*)&Dh, (void*)&Dl, (void*)&Dth, (void*)&Dtl
    };
    hipLaunchCooperativeKernel((void*)k_mega, dim3(NBLK), dim3(NTHR), args, 0, stream);
}

// Round 6
// 11684.019 us; speedup vs baseline: 5.7895x; 5.7895x over previous
//
#include <hip/hip_runtime.h>
#include <math.h>

#define N_ITERS 200
#define B_DIM 128
#define K_DIM 10000
#define KP2 10240           /* Z cols / Dth cols: 10 ksplits x 1024 */
#define KB  10048           /* Dh rows / R stride: 314 tiles x 32 */
#define D_DIM 1024
#define ALPHA_F 4.8828125e-6f   /* 0.01 / 2048 */
#define SPLITK 10

typedef unsigned short u16;
typedef __attribute__((ext_vector_type(8))) short bf16x8;
typedef __attribute__((ext_vector_type(4))) float f32x4;
#define MFMA __builtin_amdgcn_mfma_f32_16x16x32_bf16

__device__ __forceinline__ u16 f2bf(float x) {
    unsigned u = __float_as_uint(x);
    u += 0x7fff + ((u >> 16) & 1);
    return (u16)(u >> 16);
}
__device__ __forceinline__ float bf2f(u16 h) {
    return __uint_as_float(((unsigned)h) << 16);
}
__device__ __forceinline__ void split2(float x, u16& h, u16& l) {
    u16 hh = f2bf(x);
    h = hh;
    l = f2bf(x - bf2f(hh));
}
__device__ __forceinline__ int swz(int r) { return (r & 3) ^ ((r >> 2) & 1); }

__device__ __forceinline__ void gl2lds16(const u16* g, u16* l) {
    __builtin_amdgcn_global_load_lds(
        (const __attribute__((address_space(1))) unsigned int*)g,
        (__attribute__((address_space(3))) unsigned int*)l,
        16, 0, 0);
}

// ---------------------------------------------------------------------------
// Shared GEMM core: 64(m) x 32(n) tile, 128 threads (2 waves), split-bf16
// compensated, dbuf 24 KB LDS. A: 64 rows K-major; B: 32 rows K-major.
// Stage layout (u16): Ah@0(2048) Al@2048 Bh@4096(1024) Bl@5120; stride 6144.
// ---------------------------------------------------------------------------
__device__ __forceinline__ void gemm_core(
        const u16* __restrict__ Ahg, const u16* __restrict__ Alg, size_t sA, int arow0,
        const u16* __restrict__ Bhg, const u16* __restrict__ Blg, size_t sB, int brow0,
        size_t k0, int nsteps, u16* lds, int t, f32x4 acc[2][2]) {
    int lane = t & 63, quad = lane >> 4, lr = lane & 15;
    int wm = (t >> 6) * 32;
    int r1 = t >> 2, qs = t & 3;
    int r2 = r1 + 32;
    int q1 = qs ^ swz(r1);
    int q2 = qs ^ swz(r2);
    const u16* pAh1 = Ahg + (size_t)(arow0 + r1) * sA + k0 + q1 * 8;
    const u16* pAh2 = Ahg + (size_t)(arow0 + r2) * sA + k0 + q2 * 8;
    const u16* pAl1 = Alg + (size_t)(arow0 + r1) * sA + k0 + q1 * 8;
    const u16* pAl2 = Alg + (size_t)(arow0 + r2) * sA + k0 + q2 * 8;
    const u16* pBh  = Bhg + (size_t)(brow0 + r1) * sB + k0 + q1 * 8;
    const u16* pBl  = Blg + (size_t)(brow0 + r1) * sB + k0 + q1 * 8;
    int dA = t * 8;
    int offA[2], offB[2];
    #pragma unroll
    for (int mi = 0; mi < 2; ++mi) { int rr = wm + mi * 16 + lr; offA[mi] = rr * 32 + ((quad ^ swz(rr)) * 8); }
    #pragma unroll
    for (int ni = 0; ni < 2; ++ni) { int rr = ni * 16 + lr; offB[ni] = 4096 + rr * 32 + ((quad ^ swz(rr)) * 8); }
    #pragma unroll
    for (int mi = 0; mi < 2; ++mi)
        #pragma unroll
        for (int ni = 0; ni < 2; ++ni) acc[mi][ni] = (f32x4){0.f, 0.f, 0.f, 0.f};
    {   // prologue: stage 0 into buf 0
        gl2lds16(pAh1, lds + dA);
        gl2lds16(pAh2, lds + 1024 + dA);
        gl2lds16(pAl1, lds + 2048 + dA);
        gl2lds16(pAl2, lds + 3072 + dA);
        gl2lds16(pBh,  lds + 4096 + dA);
        gl2lds16(pBl,  lds + 5120 + dA);
    }
    for (int s = 0; s < nsteps; ++s) {
        __syncthreads();
        if (s + 1 < nsteps) {
            u16* b = lds + ((s + 1) & 1) * 6144;
            int c = (s + 1) * 32;
            gl2lds16(pAh1 + c, b + dA);
            gl2lds16(pAh2 + c, b + 1024 + dA);
            gl2lds16(pAl1 + c, b + 2048 + dA);
            gl2lds16(pAl2 + c, b + 3072 + dA);
            gl2lds16(pBh + c,  b + 4096 + dA);
            gl2lds16(pBl + c,  b + 5120 + dA);
        }
        u16* b = lds + (s & 1) * 6144;
        bf16x8 aH[2], aL[2], bH[2], bL[2];
        #pragma unroll
        for (int mi = 0; mi < 2; ++mi) { aH[mi] = *(const bf16x8*)&b[offA[mi]]; aL[mi] = *(const bf16x8*)&b[2048 + offA[mi]]; }
        #pragma unroll
        for (int ni = 0; ni < 2; ++ni) { bH[ni] = *(const bf16x8*)&b[offB[ni]]; bL[ni] = *(const bf16x8*)&b[1024 + offB[ni]]; }
        #pragma unroll
        for (int mi = 0; mi < 2; ++mi)
            #pragma unroll
            for (int ni = 0; ni < 2; ++ni) {
                acc[mi][ni] = MFMA(aL[mi], bH[ni], acc[mi][ni], 0, 0, 0);
                acc[mi][ni] = MFMA(aH[mi], bL[ni], acc[mi][ni], 0, 0, 0);
                acc[mi][ni] = MFMA(aH[mi], bH[ni], acc[mi][ni], 0, 0, 0);
            }
    }
    __syncthreads();
}

// ---------------------------------------------------------------------------
// init: W(=d_out incl score)=0, Zh/Zl=0, emb->Eh/El(=Uh/Ul), u0=0, scal=0
// ---------------------------------------------------------------------------
__global__ __launch_bounds__(256) void k_init(float* __restrict__ out,
                                              u16* __restrict__ Zh, u16* __restrict__ Zl,
                                              const float* __restrict__ emb,
                                              u16* __restrict__ Eh, u16* __restrict__ El,
                                              float* __restrict__ u0,
                                              float* __restrict__ scal) {
    int idx = blockIdx.x * 256 + threadIdx.x;
    int stride = gridDim.x * 256;
    for (int i = idx; i <= B_DIM * K_DIM; i += stride) out[i] = 0.0f;
    unsigned* zh = (unsigned*)Zh;
    unsigned* zl = (unsigned*)Zl;
    for (int i = idx; i < B_DIM * KP2 / 2; i += stride) { zh[i] = 0u; zl[i] = 0u; }
    for (int i = idx; i < B_DIM * D_DIM; i += stride) {
        u16 h, l; split2(emb[i], h, l);
        Eh[i] = h; El[i] = l;
    }
    for (int i = idx; i < D_DIM; i += stride) u0[i] = 0.0f;
    for (int i = idx; i < 64; i += stride) scal[i] = 0.0f;
}

// ---------------------------------------------------------------------------
// D fp32 [10000,1024] -> Dh/Dl [KB,1024] and Dth/Dtl [1024,KP2] (padded zero)
// ---------------------------------------------------------------------------
__global__ __launch_bounds__(256) void k_convertD(const float* __restrict__ D,
                                                  u16* __restrict__ Dh,
                                                  u16* __restrict__ Dl,
                                                  u16* __restrict__ Dth,
                                                  u16* __restrict__ Dtl) {
    __shared__ u16 Th[32][33], Tl[32][33];
    int tx = threadIdx.x & 31, ty = threadIdx.x >> 5;
    int k0 = blockIdx.x * 32, d0 = blockIdx.y * 32;
    #pragma unroll
    for (int r = 0; r < 4; ++r) {
        int krow = k0 + ty + r * 8;
        float val = (krow < K_DIM) ? D[(size_t)krow * D_DIM + d0 + tx] : 0.0f;
        u16 h, l; split2(val, h, l);
        if (krow < KB) {
            Dh[(size_t)krow * D_DIM + d0 + tx] = h;
            Dl[(size_t)krow * D_DIM + d0 + tx] = l;
        }
        Th[ty + r * 8][tx] = h;
        Tl[ty + r * 8][tx] = l;
    }
    __syncthreads();
    #pragma unroll
    for (int r = 0; r < 4; ++r) {
        int d = d0 + ty + r * 8;
        int k = k0 + tx;
        Dth[(size_t)d * KP2 + k] = Th[tx][ty + r * 8];
        Dtl[(size_t)d * KP2 + k] = Tl[tx][ty + r * 8];
    }
}

// ---------------------------------------------------------------------------
// u0 = ones(10000) @ D  (column sums)
// ---------------------------------------------------------------------------
__global__ __launch_bounds__(256) void k_colsum(const float* __restrict__ D,
                                                float* __restrict__ u0) {
    int t = threadIdx.x;
    int kbase = blockIdx.x * 40;
    float a0 = 0.f, a1 = 0.f, a2 = 0.f, a3 = 0.f;
    for (int k = kbase; k < kbase + 40; ++k) {
        const float* row = D + (size_t)k * D_DIM;
        a0 += row[t];
        a1 += row[t + 256];
        a2 += row[t + 512];
        a3 += row[t + 768];
    }
    atomicAdd(&u0[t], a0);
    atomicAdd(&u0[t + 256], a1);
    atomicAdd(&u0[t + 512], a2);
    atomicAdd(&u0[t + 768], a3);
}

// ---------------------------------------------------------------------------
// Gram: G[1024][1024] = Dth @ Dth^T over K=10240. grid (32 n, 16 m), 128 thr.
// ---------------------------------------------------------------------------
__global__ __launch_bounds__(128, 4) void k_gram(const u16* __restrict__ Dth,
                                                 const u16* __restrict__ Dtl,
                                                 float* __restrict__ G) {
    __shared__ __align__(16) u16 lds[12288];
    int t = threadIdx.x;
    int n0 = blockIdx.x * 32, m0 = blockIdx.y * 64;
    f32x4 acc[2][2];
    gemm_core(Dth, Dtl, KP2, m0, Dth, Dtl, KP2, n0, 0, 320, lds, t, acc);
    int lane = t & 63, quad = lane >> 4, lr = lane & 15;
    int wm = (t >> 6) * 32;
    #pragma unroll
    for (int mi = 0; mi < 2; ++mi)
        #pragma unroll
        for (int ni = 0; ni < 2; ++ni) {
            int c = n0 + ni * 16 + lr;
            #pragma unroll
            for (int r = 0; r < 4; ++r) {
                int row = m0 + wm + mi * 16 + quad * 4 + r;
                G[(size_t)row * D_DIM + c] = acc[mi][ni][r];
            }
        }
}

// ---------------------------------------------------------------------------
// One power step in u-space: u = (pw==0) ? u0 : wvin*rsqrt(Xprev);
// wvout[c] = sum_r u[r]*G[c][r]; X += wvout[c]*u[c].  grid 256 x 256.
// ---------------------------------------------------------------------------
__global__ __launch_bounds__(256) void k_pstep(const float* __restrict__ G,
                                               const float* __restrict__ u0,
                                               const float* __restrict__ wvin,
                                               float* __restrict__ wvout,
                                               float* __restrict__ scal, int pw) {
    int t = threadIdx.x;
    int c = blockIdx.x * 4 + (t >> 6);
    int lane = t & 63;
    float rsX = (pw > 0) ? rsqrtf(scal[1 + pw]) : 1.0f;
    float a = 0.f;
    const float* Gr = G + (size_t)c * D_DIM;
    #pragma unroll
    for (int j = 0; j < 16; ++j) {
        int r = lane + j * 64;
        float ur = (pw == 0) ? u0[r] : wvin[r] * rsX;
        a = fmaf(ur, Gr[r], a);
    }
    #pragma unroll
    for (int o = 32; o > 0; o >>= 1) a += __shfl_down(a, o, 64);
    if (lane == 0) {
        float uc = (pw == 0) ? u0[c] : wvin[c] * rsX;
        wvout[c] = a;
        atomicAdd(&scal[2 + pw], a * uc);
    }
}

__global__ void k_Lfin(float* __restrict__ scal) {
    float stepv = 1024.0f / sqrtf(scal[2 + 30]);
    scal[0] = stepv;
    scal[1] = stepv * ALPHA_F;
}

// ---------------------------------------------------------------------------
// G1: Up[ks][128][1024] = Z[:, ks*1024:+1024] @ Dth-slice^T
// grid (32 n-tiles of 32 d-cols, 2 m, 10 ks), 128 thr.
// ---------------------------------------------------------------------------
__global__ __launch_bounds__(128, 4) void k_g1(const u16* __restrict__ Zh,
                                               const u16* __restrict__ Zl,
                                               const u16* __restrict__ Dth,
                                               const u16* __restrict__ Dtl,
                                               float* __restrict__ Up) {
    __shared__ __align__(16) u16 lds[12288];
    int t = threadIdx.x;
    int n0 = blockIdx.x * 32, m0 = blockIdx.y * 64;
    int ks = blockIdx.z;
    f32x4 acc[2][2];
    gemm_core(Zh, Zl, KP2, m0, Dth, Dtl, KP2, n0, (size_t)ks * 1024, 32, lds, t, acc);
    int lane = t & 63, quad = lane >> 4, lr = lane & 15;
    int wm = (t >> 6) * 32;
    float* o = Up + (size_t)ks * (B_DIM * D_DIM);
    #pragma unroll
    for (int mi = 0; mi < 2; ++mi)
        #pragma unroll
        for (int ni = 0; ni < 2; ++ni) {
            int d = n0 + ni * 16 + lr;
            #pragma unroll
            for (int r = 0; r < 4; ++r) {
                int row = m0 + wm + mi * 16 + quad * 4 + r;
                o[(size_t)row * D_DIM + d] = acc[mi][ni][r];
            }
        }
}

// ---------------------------------------------------------------------------
// reduce 10 partials -> split bf16 Uh/Ul.  grid 64 x 256, 8 elems/thread.
// ---------------------------------------------------------------------------
__global__ __launch_bounds__(256) void k_reduceU(const float* __restrict__ Up,
                                                 u16* __restrict__ Uh,
                                                 u16* __restrict__ Ul) {
    int base = (blockIdx.x * 256 + threadIdx.x) * 8;
    float4 s0 = {0, 0, 0, 0}, s1 = {0, 0, 0, 0};
    #pragma unroll
    for (int s = 0; s < SPLITK; ++s) {
        const float* p = Up + (size_t)s * (B_DIM * D_DIM) + base;
        float4 a = *(const float4*)p;
        float4 b = *(const float4*)(p + 4);
        s0.x += a.x; s0.y += a.y; s0.z += a.z; s0.w += a.w;
        s1.x += b.x; s1.y += b.y; s1.z += b.z; s1.w += b.w;
    }
    float vbuf[8] = {s0.x, s0.y, s0.z, s0.w, s1.x, s1.y, s1.z, s1.w};
    union { u16 us[8]; int4 v; } h, l;
    #pragma unroll
    for (int q = 0; q < 8; ++q) split2(vbuf[q], h.us[q], l.us[q]);
    *(int4*)&Uh[base] = h.v;
    *(int4*)&Ul[base] = l.v;
}

// ---------------------------------------------------------------------------
// G2: acc[128,KB] = A[128,1024] @ Dh^T.  grid (314 n-tiles of 32, 2 m), 128 thr.
// mode 0: R = acc/n.  mode 1: fused FISTA prox (W, Zh/Zl update).
// ---------------------------------------------------------------------------
__global__ __launch_bounds__(128, 4) void k_g2(const u16* __restrict__ Ahg,
                                               const u16* __restrict__ Alg,
                                               const u16* __restrict__ Bhg,
                                               const u16* __restrict__ Blg,
                                               float* __restrict__ R,
                                               float* __restrict__ W,
                                               u16* __restrict__ Zh, u16* __restrict__ Zl,
                                               const float* __restrict__ scal,
                                               float mom, int mode, int writeW) {
    __shared__ __align__(16) u16 lds[12288];
    int t = threadIdx.x;
    int n0 = blockIdx.x * 32, i0 = blockIdx.y * 64;
    f32x4 acc[2][2];
    gemm_core(Ahg, Alg, D_DIM, i0, Bhg, Blg, D_DIM, n0, 0, 32, lds, t, acc);
    int lane = t & 63, quad = lane >> 4, lr = lane & 15;
    int wm = (t >> 6) * 32;
    const float invN = 1.0f / 1024.0f;
    if (mode == 0) {
        #pragma unroll
        for (int mi = 0; mi < 2; ++mi)
            #pragma unroll
            for (int ni = 0; ni < 2; ++ni) {
                int k = n0 + ni * 16 + lr;
                #pragma unroll
                for (int r = 0; r < 4; ++r) {
                    int i = i0 + wm + mi * 16 + quad * 4 + r;
                    R[(size_t)i * KB + k] = acc[mi][ni][r] * invN;
                }
            }
    } else {
        float stepv = scal[0], th = scal[1];
        #pragma unroll
        for (int mi = 0; mi < 2; ++mi)
            #pragma unroll
            for (int ni = 0; ni < 2; ++ni) {
                int k = n0 + ni * 16 + lr;
                #pragma unroll
                for (int r = 0; r < 4; ++r) {
                    int i = i0 + wm + mi * 16 + quad * 4 + r;
                    size_t iz = (size_t)i * KP2 + k;
                    float g = acc[mi][ni][r] * invN - R[(size_t)i * KB + k];
                    float z = bf2f(Zh[iz]) + bf2f(Zl[iz]);
                    float wold = (k < K_DIM) ? W[(size_t)i * K_DIM + k] : 0.0f;
                    float wnew = fmaxf(z - stepv * g - th, 0.0f);
                    float zn = wnew + mom * (wnew - wold);
                    if (k < K_DIM) W[(size_t)i * K_DIM + k] = wnew;
                    u16 h, l;
                    split2(writeW ? wnew : zn, h, l);
                    Zh[iz] = h; Zl[iz] = l;
                }
            }
    }
}

// ---------------------------------------------------------------------------
// score = sum_i <recon_i, emb_i> / (||recon_i|| + 1e-12)
// ---------------------------------------------------------------------------
__global__ __launch_bounds__(256) void k_score(const u16* __restrict__ Uh,
                                               const u16* __restrict__ Ul,
                                               const float* __restrict__ emb,
                                               float* __restrict__ score) {
    int wid = blockIdx.x * 4 + (threadIdx.x >> 6);
    int lane = threadIdx.x & 63;
    if (wid >= B_DIM) return;
    float rr = 0.f, re = 0.f;
    #pragma unroll
    for (int j = 0; j < D_DIM; j += 64) {
        int idx = wid * D_DIM + j + lane;
        float x = bf2f(Uh[idx]) + bf2f(Ul[idx]);
        rr = fmaf(x, x, rr);
        re = fmaf(x, emb[idx], re);
    }
    #pragma unroll
    for (int off = 32; off > 0; off >>= 1) {
        rr += __shfl_down(rr, off, 64);
        re += __shfl_down(re, off, 64);
    }
    if (lane == 0) atomicAdd(score, re / (sqrtf(rr) + 1e-12f));
}

// ---------------------------------------------------------------------------
extern "C" void kernel_launch(void* const* d_in, const int* in_sizes, int n_in,
                              void* d_out, int out_size, void* d_ws, size_t ws_size,
                              hipStream_t stream) {
    const float* emb = (const float*)d_in[0];   // [128,1024]
    const float* Dm  = (const float*)d_in[1];   // [10000,1024]
    float* out = (float*)d_out;
    float* W = out;                             // [128][10000] in d_out

    size_t off = 0;
    auto carve = [&](size_t bytes) -> void* {
        void* r = (char*)d_ws + off;
        off += (bytes + 255) & ~(size_t)255;
        return r;
    };
    float* R    = (float*)carve((size_t)B_DIM * KB * 4);               // 5.14 MB
    float* Up   = (float*)carve((size_t)SPLITK * B_DIM * D_DIM * 4);   // 5.24 MB
    u16*   Zh   = (u16*)carve((size_t)B_DIM * KP2 * 2);                // 2.62 MB
    u16*   Zl   = (u16*)carve((size_t)B_DIM * KP2 * 2);
    u16*   Uh   = (u16*)carve((size_t)B_DIM * D_DIM * 2);              // 0.26 MB
    u16*   Ul   = (u16*)carve((size_t)B_DIM * D_DIM * 2);
    float* u0   = (float*)carve(D_DIM * 4);
    float* wva  = (float*)carve(D_DIM * 4);
    float* wvb  = (float*)carve(D_DIM * 4);
    float* scal = (float*)carve(64 * 4);
    u16*   Dh   = (u16*)carve((size_t)KB * D_DIM * 2);                 // 20.6 MB
    u16*   Dl   = (u16*)carve((size_t)KB * D_DIM * 2);
    u16*   Dth  = (u16*)carve((size_t)D_DIM * KP2 * 2);                // 21.0 MB
    u16*   Dtl  = (u16*)carve((size_t)D_DIM * KP2 * 2);
    float* G    = Up;   // alias: Gram used only before FISTA touches Up

    k_init<<<512, 256, 0, stream>>>(out, Zh, Zl, emb, Uh, Ul, u0, scal);
    k_convertD<<<dim3(320, 32), 256, 0, stream>>>(Dm, Dh, Dl, Dth, Dtl);
    k_colsum<<<250, 256, 0, stream>>>(Dm, u0);
    k_gram<<<dim3(32, 16), 128, 0, stream>>>(Dth, Dtl, G);

    // ---- power iteration in u-space on the 1024x1024 Gram ----
    for (int pw = 0; pw <= 30; ++pw) {
        float* win  = (pw & 1) ? wva : wvb;
        float* wout = (pw & 1) ? wvb : wva;
        k_pstep<<<256, 256, 0, stream>>>(G, u0, win, wout, scal, pw);
    }
    k_Lfin<<<1, 1, 0, stream>>>(scal);

    // ---- R = emb @ D^T / n (A = split emb in Uh/Ul) ----
    k_g2<<<dim3(314, 2), 128, 0, stream>>>(Uh, Ul, Dh, Dl, R, W, Zh, Zl,
                                           scal, 0.0f, 0, 0);

    // ---- FISTA ----
    double t = 1.0;
    for (int it = 0; it < N_ITERS; ++it) {
        double tn = 0.5 * (1.0 + sqrt(1.0 + 4.0 * t * t));
        float mom = (float)((t - 1.0) / tn);
        t = tn;
        k_g1<<<dim3(32, 2, SPLITK), 128, 0, stream>>>(Zh, Zl, Dth, Dtl, Up);
        k_reduceU<<<64, 256, 0, stream>>>(Up, Uh, Ul);
        k_g2<<<dim3(314, 2), 128, 0, stream>>>(Uh, Ul, Dh, Dl, R, W, Zh, Zl,
                                               scal, mom, 1,
                                               (it == N_ITERS - 1) ? 1 : 0);
    }

    // ---- recon = W@D (Zh/Zl hold split W), score ----
    k_g1<<<dim3(32, 2, SPLITK), 128, 0, stream>>>(Zh, Zl, Dth, Dtl, Up);
    k_reduceU<<<64, 256, 0, stream>>>(Up, Uh, Ul);
    k_score<<<32, 256, 0, stream>>>(Uh, Ul, emb, out + (size_t)B_DIM * K_DIM);
}